// Round 6
// baseline (486.240 us; speedup 1.0000x reference)
//
#include <hip/hip_runtime.h>

// BranchRoute: score = sigmoid(x @ gate_w + gate_b); mask_i = score[:,i] > 0.5
// Equivalent: mask_i = (x . gate_w[:,i] + gate_b[i]) > 0   (sigmoid monotone, sig(0)=0.5)
// Outputs (concat flat): x0 = m0?x:0, x1 = m1?x:0, combined = x0 + x1.
//
// One block (256 threads) per row. Row elements held in registers between the
// dot-product phase and the write phase so x is fetched from HBM exactly once.
// K = D / (256*4) is a template parameter so xs[] is compile-time indexed
// (runtime-indexed per-thread arrays land in scratch — guide rule #20).
// Output stores are nontemporal: 402 MB of pure streaming writes, never
// re-read — keep them out of L2/L3. NOTE: __builtin_nontemporal_store needs a
// NATIVE vector type (ext_vector_type), not HIP's float4 class — hence f32x4.

typedef float f32x4 __attribute__((ext_vector_type(4)));

template <int K>
__global__ __launch_bounds__(256) void branch_route_kernel(
    const float* __restrict__ x,
    const float* __restrict__ gw,   // [D, 2] row-major: gw[d*2 + j]
    const float* __restrict__ gb,   // [2]
    float* __restrict__ out,        // [3, N, D] flat
    int N, int D)
{
    const int row = blockIdx.x;
    const int t = threadIdx.x;
    const long long rowbase = (long long)row * D;

    f32x4 xs[K];
    float d0 = 0.f, d1 = 0.f;

#pragma unroll
    for (int k = 0; k < K; ++k) {
        const int idx = (t + k * 256) * 4;   // element offset within row
        const f32x4 xv = *reinterpret_cast<const f32x4*>(x + rowbase + idx);
        // gw for d = idx..idx+3: interleaved [w0,w1] pairs -> two vec4s
        const f32x4 wa = *reinterpret_cast<const f32x4*>(gw + 2 * idx);
        const f32x4 wb = *reinterpret_cast<const f32x4*>(gw + 2 * idx + 4);
        xs[k] = xv;
        d0 += xv.x * wa.x + xv.y * wa.z + xv.z * wb.x + xv.w * wb.z;
        d1 += xv.x * wa.y + xv.y * wa.w + xv.z * wb.y + xv.w * wb.w;
    }

    // Reduce the two partial dots across the block (wave64 shuffle, then LDS).
#pragma unroll
    for (int off = 32; off > 0; off >>= 1) {
        d0 += __shfl_down(d0, off, 64);
        d1 += __shfl_down(d1, off, 64);
    }
    __shared__ float s0[4], s1[4];
    const int wave = t >> 6;
    if ((t & 63) == 0) { s0[wave] = d0; s1[wave] = d1; }
    __syncthreads();
    const float tot0 = s0[0] + s0[1] + s0[2] + s0[3] + gb[0];
    const float tot1 = s1[0] + s1[1] + s1[2] + s1[3] + gb[1];

    // sigmoid(z) > 0.5  <=>  z > 0
    const float m0 = (tot0 > 0.f) ? 1.f : 0.f;
    const float m1 = (tot1 > 0.f) ? 1.f : 0.f;
    const float mc = m0 + m1;

    float* __restrict__ out0 = out;
    float* __restrict__ out1 = out + (long long)N * D;
    float* __restrict__ out2 = out + 2LL * (long long)N * D;

#pragma unroll
    for (int k = 0; k < K; ++k) {
        const int idx = (t + k * 256) * 4;
        const f32x4 xv = xs[k];
        const f32x4 a = xv * m0;
        const f32x4 b = xv * m1;
        const f32x4 c = xv * mc;
        __builtin_nontemporal_store(a, reinterpret_cast<f32x4*>(out0 + rowbase + idx));
        __builtin_nontemporal_store(b, reinterpret_cast<f32x4*>(out1 + rowbase + idx));
        __builtin_nontemporal_store(c, reinterpret_cast<f32x4*>(out2 + rowbase + idx));
    }
}

extern "C" void kernel_launch(void* const* d_in, const int* in_sizes, int n_in,
                              void* d_out, int out_size, void* d_ws, size_t ws_size,
                              hipStream_t stream) {
    const float* x  = (const float*)d_in[0];
    const float* gw = (const float*)d_in[1];
    const float* gb = (const float*)d_in[2];
    float* out = (float*)d_out;

    const int D = in_sizes[1] / 2;       // gate_w is [D, 2]
    const int N = in_sizes[0] / D;       // x is [N, D]

    dim3 grid(N), block(256);
    const int K = D / (256 * 4);
    switch (K) {
        case 1: branch_route_kernel<1><<<grid, block, 0, stream>>>(x, gw, gb, out, N, D); break;
        case 2: branch_route_kernel<2><<<grid, block, 0, stream>>>(x, gw, gb, out, N, D); break;
        case 4: branch_route_kernel<4><<<grid, block, 0, stream>>>(x, gw, gb, out, N, D); break;
        case 8: branch_route_kernel<8><<<grid, block, 0, stream>>>(x, gw, gb, out, N, D); break;
        default: break; // harness shape is D=4096 -> K=4
    }
}

// Round 7
// 484.464 us; speedup vs baseline: 1.0037x; 1.0037x over previous
//
#include <hip/hip_runtime.h>

// BranchRoute: score = sigmoid(x @ gate_w + gate_b); mask_i = score[:,i] > 0.5
// Equivalent: mask_i = (x . gate_w[:,i] + gate_b[i]) > 0   (sigmoid monotone, sig(0)=0.5)
// Outputs (concat flat): x0 = m0?x:0, x1 = m1?x:0, combined = x0 + x1.
//
// One block (256 threads) per row. Row elements held in registers between the
// dot-product phase and the write phase so x is fetched from HBM exactly once.
// K = D / (256*4) is a template parameter so xs[] is compile-time indexed.
//
// R6 A/B: REMOVED nontemporal store hint. R6 profile showed harness fills
// sustain 6.3 TB/s with plain stores through L2, while our nt (L2-bypass)
// writes ran the kernel at ~2.3 TB/s. Theory: nt loses L2 write aggregation.

typedef float f32x4 __attribute__((ext_vector_type(4)));

template <int K>
__global__ __launch_bounds__(256) void branch_route_kernel(
    const float* __restrict__ x,
    const float* __restrict__ gw,   // [D, 2] row-major: gw[d*2 + j]
    const float* __restrict__ gb,   // [2]
    float* __restrict__ out,        // [3, N, D] flat
    int N, int D)
{
    const int row = blockIdx.x;
    const int t = threadIdx.x;
    const long long rowbase = (long long)row * D;

    f32x4 xs[K];
    float d0 = 0.f, d1 = 0.f;

#pragma unroll
    for (int k = 0; k < K; ++k) {
        const int idx = (t + k * 256) * 4;   // element offset within row
        const f32x4 xv = *reinterpret_cast<const f32x4*>(x + rowbase + idx);
        // gw for d = idx..idx+3: interleaved [w0,w1] pairs -> two vec4s
        const f32x4 wa = *reinterpret_cast<const f32x4*>(gw + 2 * idx);
        const f32x4 wb = *reinterpret_cast<const f32x4*>(gw + 2 * idx + 4);
        xs[k] = xv;
        d0 += xv.x * wa.x + xv.y * wa.z + xv.z * wb.x + xv.w * wb.z;
        d1 += xv.x * wa.y + xv.y * wa.w + xv.z * wb.y + xv.w * wb.w;
    }

    // Reduce the two partial dots across the block (wave64 shuffle, then LDS).
#pragma unroll
    for (int off = 32; off > 0; off >>= 1) {
        d0 += __shfl_down(d0, off, 64);
        d1 += __shfl_down(d1, off, 64);
    }
    __shared__ float s0[4], s1[4];
    const int wave = t >> 6;
    if ((t & 63) == 0) { s0[wave] = d0; s1[wave] = d1; }
    __syncthreads();
    const float tot0 = s0[0] + s0[1] + s0[2] + s0[3] + gb[0];
    const float tot1 = s1[0] + s1[1] + s1[2] + s1[3] + gb[1];

    // sigmoid(z) > 0.5  <=>  z > 0
    const float m0 = (tot0 > 0.f) ? 1.f : 0.f;
    const float m1 = (tot1 > 0.f) ? 1.f : 0.f;
    const float mc = m0 + m1;

    float* __restrict__ out0 = out;
    float* __restrict__ out1 = out + (long long)N * D;
    float* __restrict__ out2 = out + 2LL * (long long)N * D;

#pragma unroll
    for (int k = 0; k < K; ++k) {
        const int idx = (t + k * 256) * 4;
        const f32x4 xv = xs[k];
        const f32x4 a = xv * m0;
        const f32x4 b = xv * m1;
        const f32x4 c = xv * mc;
        *reinterpret_cast<f32x4*>(out0 + rowbase + idx) = a;
        *reinterpret_cast<f32x4*>(out1 + rowbase + idx) = b;
        *reinterpret_cast<f32x4*>(out2 + rowbase + idx) = c;
    }
}

extern "C" void kernel_launch(void* const* d_in, const int* in_sizes, int n_in,
                              void* d_out, int out_size, void* d_ws, size_t ws_size,
                              hipStream_t stream) {
    const float* x  = (const float*)d_in[0];
    const float* gw = (const float*)d_in[1];
    const float* gb = (const float*)d_in[2];
    float* out = (float*)d_out;

    const int D = in_sizes[1] / 2;       // gate_w is [D, 2]
    const int N = in_sizes[0] / D;       // x is [N, D]

    dim3 grid(N), block(256);
    const int K = D / (256 * 4);
    switch (K) {
        case 1: branch_route_kernel<1><<<grid, block, 0, stream>>>(x, gw, gb, out, N, D); break;
        case 2: branch_route_kernel<2><<<grid, block, 0, stream>>>(x, gw, gb, out, N, D); break;
        case 4: branch_route_kernel<4><<<grid, block, 0, stream>>>(x, gw, gb, out, N, D); break;
        case 8: branch_route_kernel<8><<<grid, block, 0, stream>>>(x, gw, gb, out, N, D); break;
        default: break; // harness shape is D=4096 -> K=4
    }
}